// Round 1
// 272.542 us; speedup vs baseline: 1.0048x; 1.0048x over previous
//
#include <hip/hip_runtime.h>

#define NPTS 2048
#define NPATCH 32
#define PTS_PER_PATCH 64            // 2048 / 32
#define FLOATS_PER_BATCH (NPTS*3)   // 6144
#define F4_PER_BATCH (FLOATS_PER_BATCH/4)  // 1536
#define N_PAIRS 528.0f              // 32*33/2
#define BPB 4                       // batches per block

// Raw barrier: wait only on LDS ops (lgkmcnt), NOT vmcnt — keeps the
// register-prefetch global loads in flight across the barrier.
// __syncthreads() would emit s_waitcnt vmcnt(0) and drain them.
// sched_barrier(0) on both sides pins LDS ops / reads to their side
// (rule #18: compiler may otherwise move ops across raw asm barriers).
__device__ __forceinline__ void lds_barrier() {
  __builtin_amdgcn_sched_barrier(0);
  asm volatile("s_waitcnt lgkmcnt(0)" ::: "memory");
  __builtin_amdgcn_s_barrier();
  __builtin_amdgcn_sched_barrier(0);
}

// One fused kernel: grid = B/4 = 2048 blocks, 256 threads.
// Thread t: patch p = t>>3, sub s = t&7.
// Loads float4 index 48p + 8k + s (k=0..5): each 8-lane group reads a
// contiguous 128B chunk -> every touched line fully consumed.
// Batch m+1's 6 float4 loads are issued BEFORE batch m is consumed
// (register double-buffer vb[2][6]); the lgkmcnt-only barrier lets them
// ride through the pair phase.
// Stats: 8-lane butterfly so ALL lanes of a patch hold mean/std in regs
// (i-side of the pair phase needs no LDS). Pair phase covers all 32x32
// cells with weight 0.5 (1.0 on diagonal): sum_{i<=j} = (S_all + S_diag)/2.
// j-side: 6 conflict-free LDS reads per cell from sms[cur][j][0..5]
// (banks (6j+c)%32 distinct across j = 8r+s).
__global__ __launch_bounds__(256) void patch_fused(
    const float* __restrict__ pcs, float* __restrict__ out, float scale) {
  const int tid = threadIdx.x;
  const int p   = tid >> 3;
  const int s   = tid & 7;

  __shared__ float sms[2][NPATCH][6];   // double-buffered: mean xyz, std xyz
  __shared__ float wpart[4];

  const size_t bstride = (size_t)gridDim.x * F4_PER_BATCH;
  const float4* pb = (const float4*)pcs + (size_t)blockIdx.x * F4_PER_BATCH
                     + 48 * p + s;

  float4 vb[2][6];
  float acc = 0.f;

  // preload batch 0
#pragma unroll
  for (int k = 0; k < 6; ++k) vb[0][k] = pb[8 * k];

#pragma unroll
  for (int m = 0; m < BPB; ++m) {
    const int cur = m & 1;

    // prefetch next batch into the other register buffer (vmcnt-only ops;
    // they stay outstanding across lds_barrier and the pair phase)
    if (m + 1 < BPB) {
      const float4* pn = pb + (size_t)(m + 1) * bstride;
#pragma unroll
      for (int k = 0; k < 6; ++k) vb[cur ^ 1][k] = pn[8 * k];
    }

    float L0 = 0.f, L1 = 0.f, L2 = 0.f;
    float Q0 = 0.f, Q1 = 0.f, Q2 = 0.f;

    // coordinate of v[k].{x,y,z} is ((2k + j) + s) % 3; w shares with x.
#define ACC(k, a, bb, c)                                                 \
    { float x = vb[cur][k].x, y = vb[cur][k].y,                          \
            z = vb[cur][k].z, w = vb[cur][k].w;                          \
      L##a += x + w; Q##a = fmaf(x, x, Q##a); Q##a = fmaf(w, w, Q##a);   \
      L##bb += y;    Q##bb = fmaf(y, y, Q##bb);                          \
      L##c += z;     Q##c = fmaf(z, z, Q##c); }
    ACC(0, 0, 1, 2)
    ACC(1, 2, 0, 1)
    ACC(2, 1, 2, 0)
    ACC(3, 0, 1, 2)
    ACC(4, 2, 0, 1)
    ACC(5, 1, 2, 0)
#undef ACC

    // Un-rotate: L[i] holds true coordinate (i + s) % 3.
    float sx, sy, sz, sxx, syy, szz;
    const int s3 = s % 3;
    if (s3 == 0)      { sx = L0; sy = L1; sz = L2; sxx = Q0; syy = Q1; szz = Q2; }
    else if (s3 == 1) { sx = L2; sy = L0; sz = L1; sxx = Q2; syy = Q0; szz = Q1; }
    else              { sx = L1; sy = L2; sz = L0; sxx = Q1; syy = Q2; szz = Q0; }

    // butterfly across the 8 threads of this patch: ALL lanes get the sums
#pragma unroll
    for (int off = 1; off <= 4; off <<= 1) {
      sx  += __shfl_xor(sx,  off, 8);
      sy  += __shfl_xor(sy,  off, 8);
      sz  += __shfl_xor(sz,  off, 8);
      sxx += __shfl_xor(sxx, off, 8);
      syy += __shfl_xor(syy, off, 8);
      szz += __shfl_xor(szz, off, 8);
    }

    const float inv_n   = 1.0f / PTS_PER_PATCH;
    const float inv_nm1 = 1.0f / (PTS_PER_PATCH - 1);
    const float mx = sx * inv_n, my = sy * inv_n, mz = sz * inv_n;
    const float tx = sqrtf(fmaxf((sxx - sx * sx * inv_n) * inv_nm1, 0.f));
    const float ty = sqrtf(fmaxf((syy - sy * sy * inv_n) * inv_nm1, 0.f));
    const float tz = sqrtf(fmaxf((szz - sz * sz * inv_n) * inv_nm1, 0.f));

    if (s == 0) {
      float* row = &sms[cur][p][0];
      row[0] = mx; row[1] = my; row[2] = mz;
      row[3] = tx; row[4] = ty; row[5] = tz;
    }
    // one barrier per batch: write buf[cur] -> read buf[cur]. Writes to
    // buf[cur^1] next iteration are ordered vs. this buffer's readers two
    // iterations back by the intervening barrier (double-buffer invariant).
    lds_barrier();

    // pair phase: thread (p,s) handles cells (i=p, j=s+8r), r=0..3.
    // i-side (mx..tz) is in registers; j-side is 6 conflict-free LDS reads.
    // sum_{i<=j} norm = 0.5*sum_all + 0.5*sum_diag.
#pragma unroll
    for (int r = 0; r < 4; ++r) {
      const int j = s + 8 * r;
      const float* row = &sms[cur][j][0];
      const float dx = fabsf(mx - row[0]);
      const float dy = fabsf(my - row[1]);
      const float dz = fabsf(mz - row[2]);
      const float rx = fmaxf((tx + row[3]) - dx, 0.f);
      const float ry = fmaxf((ty + row[4]) - dy, 0.f);
      const float rz = fmaxf((tz + row[5]) - dz, 0.f);
      const float nrm = sqrtf(fmaf(rx, rx, fmaf(ry, ry, rz * rz)));
      acc += (p == j ? 1.0f : 0.5f) * nrm;
    }
  }

  // block reduce (4 waves) — once per block, then ONE atomic per block
#pragma unroll
  for (int off = 32; off >= 1; off >>= 1) acc += __shfl_down(acc, off);
  if ((tid & 63) == 0) wpart[tid >> 6] = acc;
  __syncthreads();
  if (tid == 0)
    atomicAdd(out, (wpart[0] + wpart[1] + wpart[2] + wpart[3]) * scale);
}

extern "C" void kernel_launch(void* const* d_in, const int* in_sizes, int n_in,
                              void* d_out, int out_size, void* d_ws, size_t ws_size,
                              hipStream_t stream) {
  const float* pcs = (const float*)d_in[0];
  float* out = (float*)d_out;

  const int B = in_sizes[0] / FLOATS_PER_BATCH;   // 8192
  const int nblocks = B / BPB;                    // 2048
  const float scale = 1.0f / (N_PAIRS * (float)B);

  // out is poisoned between iterations: zero it with a 4-byte graph memset
  // node (capture-legal), then accumulate block partials atomically.
  hipMemsetAsync(out, 0, sizeof(float), stream);
  patch_fused<<<nblocks, 256, 0, stream>>>(pcs, out, scale);
}